// Round 2
// baseline (274.011 us; speedup 1.0000x reference)
//
#include <hip/hip_runtime.h>

// Problem constants
#define MDIM 8192
#define IDIM 1024
#define ODIM 1024
#define D1   9            // DEGREE+1
#define KDIM (IDIM * D1)  // 9216, k = d*1024 + i ordering

typedef _Float16 half8   __attribute__((ext_vector_type(8)));
typedef _Float16 half2v  __attribute__((ext_vector_type(2)));
typedef float    float4v __attribute__((ext_vector_type(4)));

#define BSCALE 256.0f     // pre-scale B into f16-normal range (exact pow2)
#define INV_BSCALE (1.0f / 256.0f)
#define USCALE 5.123105625617661f    // sqrt(17) + 1
#define H0C 0.7511255444649425f     // pi^-1/4
#define SQRT2 1.4142135623730951f   // h1 = sqrt2 * u * h0

// ---------------------------------------------------------------------------
// hermite9 (fp32) — naive fallback only.
// ---------------------------------------------------------------------------
__device__ __forceinline__ void hermite9(float xv, float h[D1]) {
    float ax = fabsf(xv);
    float t  = __expf(-2.0f * ax);
    float th = (1.0f - t) / (1.0f + t);
    th = copysignf(th, xv);
    float u = th * USCALE;
    float g = __expf(-0.5f * u * u);
    h[0] = H0C * g;
    h[1] = SQRT2 * H0C * u * g;
    const float c1[D1] = {0.f, 0.f, 1.0f, 0.8164965809277260f, 0.7071067811865476f,
                          0.6324555320336759f, 0.5773502691896258f, 0.5345224838248488f, 0.5f};
    const float c2[D1] = {0.f, 0.f, 0.7071067811865476f, 0.8164965809277260f, 0.8660254037844386f,
                          0.8944271909999159f, 0.9128709291752769f, 0.9258200997725514f, 0.9354143466934853f};
#pragma unroll
    for (int d = 2; d < D1; ++d) h[d] = c1[d] * u * h[d - 1] - c2[d] * h[d - 2];
}

// ---------------------------------------------------------------------------
// prep_b v2: LDS transpose, 32i x 32o tile, padded LDS, coalesced both phases.
// ---------------------------------------------------------------------------
__global__ __launch_bounds__(256) void prep_b(const float* __restrict__ C,
                                              _Float16* __restrict__ Bt) {
    __shared__ float lds[288 * 33];
    const int t  = threadIdx.x;
    const int ti = blockIdx.x & 31;
    const int to = blockIdx.x >> 5;
    const float* base = C + (size_t)ti * 32 * 9216 + (size_t)to * 32 * 9;
#pragma unroll
    for (int j = 0; j < 36; ++j) {
        int f   = t + 256 * j;
        int row = f / 288;
        int col = f - row * 288;
        lds[col * 33 + row] = base[(size_t)row * 9216 + col];
    }
    __syncthreads();
    _Float16* bb = Bt + (size_t)to * 32 * KDIM + ti * 32;
#pragma unroll
    for (int j = 0; j < 36; ++j) {
        int e   = t + 256 * j;
        int i   = e & 31;
        int odp = e >> 5;
        int ol  = odp / 9;
        int d   = odp - ol * 9;
        bb[(size_t)ol * KDIM + d * IDIM + i] = (_Float16)(lds[odp * 33 + i] * BSCALE);
    }
}

// ---------------------------------------------------------------------------
// prep_u: x fp32 -> u = USCALE*tanh(x) and h0 = pi^-1/4 * exp(-u^2/2), both f16.
// ---------------------------------------------------------------------------
__global__ __launch_bounds__(256) void prep_u(const float* __restrict__ x,
                                              _Float16* __restrict__ U,
                                              _Float16* __restrict__ H0) {
    size_t t = (size_t)blockIdx.x * 256 + threadIdx.x;
    const float4* xp = (const float4*)(x + t * 8);
    float4 a0 = xp[0], a1 = xp[1];
    float xv[8] = {a0.x, a0.y, a0.z, a0.w, a1.x, a1.y, a1.z, a1.w};
    half8 uu, hh;
#pragma unroll
    for (int e = 0; e < 8; ++e) {
        float v  = xv[e];
        float t2 = __expf(-2.0f * fabsf(v));
        float th = (1.0f - t2) / (1.0f + t2);
        float u  = copysignf(th, v) * USCALE;
        float g  = __expf(-0.5f * u * u);
        uu[e] = (_Float16)u;
        hh[e] = (_Float16)(H0C * g);
    }
    *(half8*)(U  + t * 8) = uu;
    *(half8*)(H0 + t * 8) = hh;
}

// ---------------------------------------------------------------------------
// gemm_fused3: counted-vmcnt pipeline (T3+T4+T5).
//   Bs triple-buffered, DMA issued TWO windows ahead; never drains vmcnt in
//   the main loop (steady state: s_waitcnt vmcnt(4), vmcnt(12) on UH windows).
//   As single-buffered, two raw s_barriers per window:
//     region1: frag ds_reads + 32 MFMA (setprio 1) + hermite E-phase (VGPR)
//     region2: writeA (next window's A-tile) + DMA(t+2) [+ UH prefetch @ d==6]
//   Hermite recurrence runs 2 windows ahead (E(t) produces h for window t+2).
//   128x128 tile, 4 waves 2x2, 16x16x32 f16 MFMA, XOR-swizzled LDS.
// ---------------------------------------------------------------------------
__global__ __launch_bounds__(256, 2) void gemm_fused3(
    const _Float16* __restrict__ U,    // [8192][1024] f16
    const _Float16* __restrict__ H0,   // [8192][1024] f16
    const _Float16* __restrict__ Bt,   // [ODIM][KDIM], pre-scaled by 256
    float* __restrict__ out)           // [8192][ODIM]
{
    const int tid = threadIdx.x;
    const int w = tid >> 6;
    const int l = tid & 63;
    const int bn = blockIdx.x;    // n-tile 0..7
    const int bm = blockIdx.y;    // m-tile 0..63

    __shared__ _Float16 As[128 * 64];        // 16 KB, single buffer
    __shared__ _Float16 Bs[3][128 * 64];     // 48 KB, triple buffer

    // Bs staging: lane l, rep rr loads 16B; stored kgrp = (l&7)^(l>>3)
    const int lrow8 = l >> 3;
    const int kgrp  = (l & 7) ^ lrow8;
    const _Float16* Bg = Bt + ((size_t)(bn * 128 + w * 8 + lrow8) * KDIM + kgrp * 8);

    // compute-side fragment indices
    const int q   = l >> 4;
    const int m16 = l & 15;
    const int s3  = m16 & 7;
    const int wm  = w >> 1, wn = w & 1;

    // hermite producer: 2 threads per A-row, 32 i's each
    const int r  = tid >> 1;
    const int ih = tid & 1;
    const int r7 = r & 7;
    const size_t urow = (((size_t)(bm * 128 + r)) << 10) + ih * 32;

    constexpr float c1a[D1] = {0.f, 0.f, 1.0f, 0.8164965809277260f, 0.7071067811865476f,
                               0.6324555320336759f, 0.5773502691896258f, 0.5345224838248488f, 0.5f};
    constexpr float c2a[D1] = {0.f, 0.f, 0.7071067811865476f, 0.8164965809277260f, 0.8660254037844386f,
                               0.8944271909999159f, 0.9128709291752769f, 0.9258200997725514f, 0.9354143466934853f};

    half2v u2[16], hA[16], hB[16], ht[16];
    half8  ub[4], hb[4];
    const half2v sq2 = half2v{(_Float16)SQRT2, (_Float16)SQRT2};

    // write 32 ht values into As row r, XOR-swizzled
    _Float16* arow = &As[r * 64];
    auto writeA = [&](const half2v* hts) {
#pragma unroll
        for (int c = 0; c < 4; ++c) {
            int slot = (ih * 4 + c) ^ r7;
            half8 vv;
#pragma unroll
            for (int pp = 0; pp < 4; ++pp) {
                vv[2*pp+0] = hts[4*c+pp][0];
                vv[2*pp+1] = hts[4*c+pp][1];
            }
            *(half8*)(arow + slot * 8) = vv;
        }
    };

    float4v acc[4][4] = {};

    // ---- prologue ---------------------------------------------------------
    // sync-load u/h0 for i-block 0; state: hA=h0, hB=h1, ht=h1 (for window 1)
    {
        const half8* up = (const half8*)(U  + urow);
        const half8* hp = (const half8*)(H0 + urow);
#pragma unroll
        for (int a = 0; a < 4; ++a) { ub[a] = up[a]; hb[a] = hp[a]; }
#pragma unroll
        for (int a = 0; a < 4; ++a)
#pragma unroll
            for (int b = 0; b < 4; ++b) {
                u2[4*a+b] = half2v{ub[a][2*b], ub[a][2*b+1]};
                hA[4*a+b] = half2v{hb[a][2*b], hb[a][2*b+1]};
            }
#pragma unroll
        for (int p = 0; p < 16; ++p) { hB[p] = sq2 * u2[p] * hA[p]; ht[p] = hB[p]; }
    }
    // DMA batch(0) -> Bs[0] (koff 0) and batch(1) -> Bs[1] (koff 1024)
#pragma unroll
    for (int rr = 0; rr < 4; ++rr)
        __builtin_amdgcn_global_load_lds(
            (const __attribute__((address_space(1))) void*)(Bg + (size_t)(rr * 32) * KDIM),
            (__attribute__((address_space(3))) void*)((char*)&Bs[0][0] + (rr * 4 + w) * 1024),
            16, 0, 0);
#pragma unroll
    for (int rr = 0; rr < 4; ++rr)
        __builtin_amdgcn_global_load_lds(
            (const __attribute__((address_space(1))) void*)(Bg + (size_t)(rr * 32) * KDIM + IDIM),
            (__attribute__((address_space(3))) void*)((char*)&Bs[1][0] + (rr * 4 + w) * 1024),
            16, 0, 0);
    writeA(hA);  // As <- h0
    // batch(0) must land; batch(1) stays in flight (steady-state invariant)
    asm volatile("s_waitcnt vmcnt(4) lgkmcnt(0)" ::: "memory");
    __builtin_amdgcn_s_barrier();
    asm volatile("" ::: "memory");

    // ---- one pipeline window (t = ib*9 + d) -------------------------------
    // region1: MFMA on As / Bs[d%3]; E computes htn = h_{deg(t+2)}
    // region2: writeA(ht = h_{deg(t+1)}); [UH prefetch]; DMA batch(t+2)
    auto window = [&](int ib, int d, bool do_e, bool do_wa, bool do_uh,
                      bool do_dma, int waitN, bool do_sync2, bool do_sync1) {
        const int cbuf = d % 3;

        // ---- region 1: MFMA
        __builtin_amdgcn_s_setprio(1);
#pragma unroll
        for (int ko = 0; ko < 2; ++ko) {
            const int slot = (q + 4 * ko) ^ s3;
            half8 af[4], bf[4];
#pragma unroll
            for (int i = 0; i < 4; ++i) {
                af[i] = *(const half8*)&As[(wm * 64 + i * 16 + m16) * 64 + slot * 8];
                bf[i] = *(const half8*)&Bs[cbuf][(wn * 64 + i * 16 + m16) * 64 + slot * 8];
            }
#pragma unroll
            for (int i = 0; i < 4; ++i)
#pragma unroll
                for (int j = 0; j < 4; ++j)
                    acc[i][j] = __builtin_amdgcn_mfma_f32_16x16x32_f16(af[i], bf[j], acc[i][j], 0, 0, 0);
        }
        __builtin_amdgcn_s_setprio(0);

        // ---- region 1: E-phase (pure VGPR, overlaps MFMA pipe in-wave)
        half2v htn[16];
        if (do_e) {
            const int t2d = (d <= 6) ? (d + 2) : (d - 7);   // degree of window t+2
            if (t2d == 0) {
                // new i-block: unpack prefetched u/h0
#pragma unroll
                for (int a = 0; a < 4; ++a)
#pragma unroll
                    for (int b = 0; b < 4; ++b) {
                        u2[4*a+b]  = half2v{ub[a][2*b], ub[a][2*b+1]};
                        htn[4*a+b] = half2v{hb[a][2*b], hb[a][2*b+1]};
                    }
#pragma unroll
                for (int p = 0; p < 16; ++p) hB[p] = htn[p];
            } else if (t2d == 1) {
#pragma unroll
                for (int p = 0; p < 16; ++p) {
                    htn[p] = sq2 * u2[p] * hB[p];
                    hA[p] = hB[p]; hB[p] = htn[p];
                }
            } else {
                const half2v c1v = half2v{(_Float16)c1a[t2d], (_Float16)c1a[t2d]};
                const half2v c2v = half2v{(_Float16)c2a[t2d], (_Float16)c2a[t2d]};
#pragma unroll
                for (int p = 0; p < 16; ++p) {
                    half2v tt = u2[p] * hB[p];
                    htn[p] = c1v * tt - c2v * hA[p];
                    hA[p] = hB[p]; hB[p] = htn[p];
                }
            }
        }

        if (do_sync2) {
            asm volatile("s_waitcnt lgkmcnt(0)" ::: "memory");  // my frag reads retired
            __builtin_amdgcn_s_barrier();                       // barrier2
            asm volatile("" ::: "memory");
        }

        // ---- region 2
        if (do_wa) writeA(ht);            // publish h_{deg(t+1)} (old ht)
        if (do_e) {
#pragma unroll
            for (int p = 0; p < 16; ++p) ht[p] = htn[p];
        }
        if (do_uh) {                      // prefetch u/h0 of i-block ib+1
            const half8* up = (const half8*)(U  + urow + (size_t)(ib + 1) * 64);
            const half8* hp = (const half8*)(H0 + urow + (size_t)(ib + 1) * 64);
#pragma unroll
            for (int a = 0; a < 4; ++a) { ub[a] = up[a]; hb[a] = hp[a]; }
        }
        if (do_dma) {                     // batch(t+2) -> Bs[(t+2)%3]
            const int nkoff = (d <= 6) ? ((d + 2) * IDIM + ib * 64)
                                       : ((d - 7) * IDIM + ib * 64 + 64);
            const int nbuf = (d + 2) % 3;
#pragma unroll
            for (int rr = 0; rr < 4; ++rr)
                __builtin_amdgcn_global_load_lds(
                    (const __attribute__((address_space(1))) void*)(Bg + (size_t)(rr * 32) * KDIM + nkoff),
                    (__attribute__((address_space(3))) void*)((char*)&Bs[nbuf][0] + (rr * 4 + w) * 1024),
                    16, 0, 0);
        }
        if (do_sync1) {
            // batch(t+1) must land; batch(t+2) (+UH) stay in flight
            if (waitN == 12)     asm volatile("s_waitcnt vmcnt(12) lgkmcnt(0)" ::: "memory");
            else if (waitN == 4) asm volatile("s_waitcnt vmcnt(4) lgkmcnt(0)" ::: "memory");
            else                 asm volatile("s_waitcnt vmcnt(0) lgkmcnt(0)" ::: "memory");
            __builtin_amdgcn_s_barrier();                       // barrier1(t+1)
            asm volatile("" ::: "memory");
        }
    };

    // ---- main loop: ib 0..14, full pipeline, no runtime guards ------------
    for (int ib = 0; ib < 15; ++ib) {
#pragma unroll
        for (int d = 0; d < D1; ++d)
            window(ib, d, true, true, (d == 6), true, (d == 6) ? 12 : 4, true, true);
    }
    // ---- tail: ib == 15 ---------------------------------------------------
    {
#pragma unroll
        for (int d = 0; d < 6; ++d)
            window(15, d, true, true, false, true, 4, true, true);
        window(15, 6, true,  true,  false, true,  4, true, true);   // t=141: issues batch(143)
        window(15, 7, false, true,  false, false, 0, true, true);   // t=142: drain batch(143)
        window(15, 8, false, false, false, false, 0, false, false); // t=143: last MFMAs
    }

    // epilogue: D row = quad*4 + reg, col = lane&15 (m89-verified layout)
#pragma unroll
    for (int i = 0; i < 4; ++i) {
        int row = bm * 128 + wm * 64 + i * 16 + q * 4;
#pragma unroll
        for (int j = 0; j < 4; ++j) {
            int col = bn * 128 + wn * 64 + j * 16 + m16;
            float* op = out + (size_t)row * ODIM + col;
#pragma unroll
            for (int r2 = 0; r2 < 4; ++r2)
                op[(size_t)r2 * ODIM] = acc[i][j][r2] * INV_BSCALE;
        }
    }
}

// ---------------------------------------------------------------------------
// naive fallback (only if workspace can't hold Bt + U + H0, 52.4 MB)
// ---------------------------------------------------------------------------
__global__ void naive_kernel(const float* __restrict__ x, const float* __restrict__ C,
                             float* __restrict__ out) {
    __shared__ float hb[IDIM * D1];
    int b = blockIdx.x;
    int tid = threadIdx.x;
    for (int i = tid; i < IDIM; i += 256) {
        float h[D1];
        hermite9(x[(size_t)b * IDIM + i], h);
#pragma unroll
        for (int d = 0; d < D1; ++d) hb[i * D1 + d] = h[d];
    }
    __syncthreads();
    for (int o = tid; o < ODIM; o += 256) {
        float acc = 0.f;
        for (int i = 0; i < IDIM; ++i) {
            const float* cp = C + ((size_t)i * ODIM + o) * D1;
            const float* hp = hb + i * D1;
#pragma unroll
            for (int d = 0; d < D1; ++d) acc += hp[d] * cp[d];
        }
        out[(size_t)b * ODIM + o] = acc;
    }
}

// ---------------------------------------------------------------------------
extern "C" void kernel_launch(void* const* d_in, const int* in_sizes, int n_in,
                              void* d_out, int out_size, void* d_ws, size_t ws_size,
                              hipStream_t stream) {
    const float* x      = (const float*)d_in[0];   // [8192][1024]
    const float* coeffs = (const float*)d_in[1];   // [1024][1024][9]
    float* out = (float*)d_out;                    // [8192][1024]

    const size_t bt_bytes = (size_t)ODIM * KDIM * sizeof(_Float16);   // 18.9 MB
    const size_t u_bytes  = (size_t)MDIM * IDIM * sizeof(_Float16);   // 16.8 MB

    if (ws_size >= bt_bytes + 2 * u_bytes) {
        _Float16* Bt = (_Float16*)d_ws;
        _Float16* Uv = (_Float16*)((char*)d_ws + bt_bytes);
        _Float16* H0 = (_Float16*)((char*)d_ws + bt_bytes + u_bytes);
        hipLaunchKernelGGL(prep_b, dim3(1024), dim3(256), 0, stream, coeffs, Bt);
        hipLaunchKernelGGL(prep_u, dim3((MDIM * IDIM) / 2048), dim3(256), 0, stream, x, Uv, H0);
        hipLaunchKernelGGL(gemm_fused3, dim3(8, 64), dim3(256), 0, stream, Uv, H0, Bt, out);
    } else {
        hipLaunchKernelGGL(naive_kernel, dim3(MDIM), dim3(256), 0, stream, x, coeffs, out);
    }
}